// Round 1
// baseline (334.271 us; speedup 1.0000x reference)
//
#include <hip/hip_runtime.h>
#include <hip/hip_bf16.h>

// CrossModalMDTA on gfx950.
// Pipeline: [cvt weights->bf16] -> conv1x1 GEMM (MFMA bf16) -> depthwise 3x3
// (+ fused row-norm partials) -> gram G=q.k^T (MFMA, chunked partials) ->
// softmax + fold w_out into M = W_out*blockdiag(attn) -> final GEMM out = M @ v.

typedef __attribute__((ext_vector_type(8))) short short8;   // 8 x bf16 (4 VGPR)
typedef __attribute__((ext_vector_type(4))) float f32x4;    // MFMA accum

static __device__ __forceinline__ float b2f(unsigned short u) {
    return __uint_as_float(((unsigned)u) << 16);
}
static __device__ __forceinline__ unsigned short f2b(float f) {
    unsigned u = __float_as_uint(f);
    u += 0x7FFFu + ((u >> 16) & 1u);          // RNE
    return (unsigned short)(u >> 16);
}

__global__ void cvt_f2b_kernel(const float* __restrict__ src,
                               unsigned short* __restrict__ dst, int n) {
    int i = blockIdx.x * blockDim.x + threadIdx.x;
    if (i < n) dst[i] = f2b(src[i]);
}

// ---------------------------------------------------------------------------
// conv1x1 as GEMM: C[(y*192+m), n] = sum_k A[(y*192+m), k] * B[k, n], K=192.
// Block: 256 thr (4 waves), tile BM=192 x BN=64. Wave w owns rows [48w,48w+48).
// B tile (32 x 64) staged to LDS as fp32 [32][73] (73 => conflict-free frag reads).
// ---------------------------------------------------------------------------
template<typename Bty, typename Oty>
__global__ void __launch_bounds__(256) conv_gemm(
    const unsigned short* __restrict__ A,   // bf16 [.., M, 192]
    const Bty* __restrict__ B,              // [.., 192, N] fp32 or bf16
    Oty* __restrict__ C,                    // [.., M, N] bf16(ushort) or fp32
    long aStride, long bStride, long cStride, int batch0)
{
    constexpr int N = 16384;
    constexpr int K = 192;
    const int b = batch0 + blockIdx.z;
    A += (long)b * aStride + (long)blockIdx.y * 192 * K;
    B += (long)b * bStride;
    C += (long)b * cStride + (long)blockIdx.y * 192 * (long)N;

    const int tid  = threadIdx.x;
    const int wave = tid >> 6;
    const int lane = tid & 63;
    const int l15  = lane & 15;
    const int g    = lane >> 4;
    const int n0   = blockIdx.x * 64;

    __shared__ float Bs[32][73];

    f32x4 acc[3][4];
#pragma unroll
    for (int i = 0; i < 3; ++i)
#pragma unroll
        for (int j = 0; j < 4; ++j) acc[i][j] = {0.f, 0.f, 0.f, 0.f};

    for (int k0 = 0; k0 < K; k0 += 32) {
        // stage B tile [32 x 64] -> LDS fp32
#pragma unroll
        for (int ii = 0; ii < 2; ++ii) {
            const int idx = tid * 2 + ii;         // 0..511 float4-slots
            const int kk  = idx >> 4;
            const int n4  = (idx & 15) * 4;
            float f0, f1, f2, f3;
            if constexpr (sizeof(Bty) == 4) {
                const float4 v = *reinterpret_cast<const float4*>(
                    B + (long)(k0 + kk) * N + n0 + n4);
                f0 = v.x; f1 = v.y; f2 = v.z; f3 = v.w;
            } else {
                const ushort4 v = *reinterpret_cast<const ushort4*>(
                    B + (long)(k0 + kk) * N + n0 + n4);
                f0 = b2f(v.x); f1 = b2f(v.y); f2 = b2f(v.z); f3 = b2f(v.w);
            }
            Bs[kk][n4 + 0] = f0; Bs[kk][n4 + 1] = f1;
            Bs[kk][n4 + 2] = f2; Bs[kk][n4 + 3] = f3;
        }
        __syncthreads();

        short8 af[3];
#pragma unroll
        for (int mt = 0; mt < 3; ++mt)
            af[mt] = *reinterpret_cast<const short8*>(
                A + (long)(wave * 48 + mt * 16 + l15) * K + k0 + g * 8);

#pragma unroll
        for (int nt = 0; nt < 4; ++nt) {
            short8 bf;
#pragma unroll
            for (int i = 0; i < 8; ++i)
                bf[i] = (short)f2b(Bs[g * 8 + i][nt * 16 + l15]);
#pragma unroll
            for (int mt = 0; mt < 3; ++mt)
                acc[mt][nt] = __builtin_amdgcn_mfma_f32_16x16x32_bf16(
                    af[mt], bf, acc[mt][nt], 0, 0, 0);
        }
        __syncthreads();
    }

    // epilogue: D row = (lane>>4)*4 + r, col = lane&15  (verified m89/m91 layout)
#pragma unroll
    for (int mt = 0; mt < 3; ++mt) {
#pragma unroll
        for (int nt = 0; nt < 4; ++nt) {
            const int row = wave * 48 + mt * 16 + g * 4;
            const int col = n0 + nt * 16 + l15;
#pragma unroll
            for (int r = 0; r < 4; ++r) {
                const float v = acc[mt][nt][r];
                if constexpr (sizeof(Oty) == 4)
                    C[(long)(row + r) * N + col] = v;
                else
                    C[(long)(row + r) * N + col] = f2b(v);
            }
        }
    }
}

// ---------------------------------------------------------------------------
// depthwise 3x3 (SAME, zero pad), bf16 in/out, fp32 accum.
// Also emits per-(b,channel) sum-of-squares partials (32 waves/channel) for the
// l2-norms (only channels < 192, i.e. q and k).
// ---------------------------------------------------------------------------
__global__ void __launch_bounds__(256) dw3x3(
    const unsigned short* __restrict__ src,
    unsigned short* __restrict__ dst,
    const float* __restrict__ wdw,          // [C][9] fp32
    float* __restrict__ normPart,           // [B][192][32] fp32 (or unused rows)
    int C, long srcStride, long dstStride, int batch0)
{
    const int b  = batch0 + blockIdx.z;
    const int t  = blockIdx.x * 256 + threadIdx.x;
    const int w0 = (t & 15) * 8;
    const int hh = (t >> 4) & 127;
    const int c  = t >> 11;                  // 2048 threads per channel
    if (c >= C) return;

    const unsigned short* s = src + (long)b * srcStride + ((long)c << 14);
    float wt[9];
#pragma unroll
    for (int i = 0; i < 9; ++i) wt[i] = wdw[c * 9 + i];

    float acc[8] = {0, 0, 0, 0, 0, 0, 0, 0};
#pragma unroll
    for (int dy = 0; dy < 3; ++dy) {
        const int hy = hh + dy - 1;
        if (hy < 0 || hy > 127) continue;
        const unsigned short* row = s + hy * 128 + w0;
        float r[10];
        const short8 v = *reinterpret_cast<const short8*>(row);
#pragma unroll
        for (int i = 0; i < 8; ++i) r[i + 1] = b2f((unsigned short)v[i]);
        r[0] = (w0 > 0)   ? b2f(row[-1]) : 0.f;
        r[9] = (w0 < 120) ? b2f(row[8])  : 0.f;
#pragma unroll
        for (int j = 0; j < 8; ++j)
            acc[j] += wt[dy*3+0]*r[j] + wt[dy*3+1]*r[j+1] + wt[dy*3+2]*r[j+2];
    }

    short8 o;
#pragma unroll
    for (int j = 0; j < 8; ++j) o[j] = (short)f2b(acc[j]);
    *reinterpret_cast<short8*>(dst + (long)b * dstStride + ((long)c << 14)
                               + hh * 128 + w0) = o;

    // fused norm partials (exact fp32, pre-rounding)
    if (c < 192) {
        float ssq = 0.f;
#pragma unroll
        for (int j = 0; j < 8; ++j) ssq += acc[j] * acc[j];
#pragma unroll
        for (int ofs = 1; ofs < 64; ofs <<= 1) ssq += __shfl_xor(ssq, ofs);
        if ((threadIdx.x & 63) == 0)
            normPart[((long)b * 192 + c) * 32 + ((t & 2047) >> 6)] = ssq;
    }
}

// ---------------------------------------------------------------------------
// Gram: G[d,e] = sum_n q[d,n]*k[e,n] per (b,h), N chunked into 16 x 1024.
// Block = 4 waves, each wave reduces 256 cols via 8 MFMA k-steps (9 tiles).
// Writes per-(b,h,chunk) fp32 partial [48*48] (no atomics -> deterministic).
// ---------------------------------------------------------------------------
__global__ void __launch_bounds__(256) gram_kernel(
    const unsigned short* __restrict__ q,    // [B,192,N] bf16
    const unsigned short* __restrict__ kv,   // [B,384,N] bf16 (k = first 192)
    float* __restrict__ Gpart)               // [B,4,16,2304]
{
    constexpr long N = 16384;
    const int chunk = blockIdx.x, h = blockIdx.y, b = blockIdx.z;
    const int tid = threadIdx.x;
    const int wave = tid >> 6, lane = tid & 63;
    const int l15 = lane & 15, g = lane >> 4;
    const unsigned short* qp = q  + ((long)b * 192 + h * 48) * N;
    const unsigned short* kp = kv + ((long)b * 384 + h * 48) * N;
    const int nbase = chunk * 1024 + wave * 256;

    f32x4 acc[3][3];
#pragma unroll
    for (int i = 0; i < 3; ++i)
#pragma unroll
        for (int j = 0; j < 3; ++j) acc[i][j] = {0.f, 0.f, 0.f, 0.f};

    for (int s = 0; s < 8; ++s) {
        const long n0 = nbase + s * 32 + g * 8;
        short8 af[3], bf[3];
#pragma unroll
        for (int mt = 0; mt < 3; ++mt)
            af[mt] = *reinterpret_cast<const short8*>(qp + (long)(mt*16 + l15) * N + n0);
#pragma unroll
        for (int nt = 0; nt < 3; ++nt)
            bf[nt] = *reinterpret_cast<const short8*>(kp + (long)(nt*16 + l15) * N + n0);
#pragma unroll
        for (int mt = 0; mt < 3; ++mt)
#pragma unroll
            for (int nt = 0; nt < 3; ++nt)
                acc[mt][nt] = __builtin_amdgcn_mfma_f32_16x16x32_bf16(
                    af[mt], bf[nt], acc[mt][nt], 0, 0, 0);
    }

    __shared__ float Gt[4][2304];
#pragma unroll
    for (int mt = 0; mt < 3; ++mt)
#pragma unroll
        for (int nt = 0; nt < 3; ++nt)
#pragma unroll
            for (int r = 0; r < 4; ++r)
                Gt[wave][(mt*16 + g*4 + r) * 48 + nt*16 + l15] = acc[mt][nt][r];
    __syncthreads();

    float* gout = Gpart + (((long)(b * 4 + h)) * 16 + chunk) * 2304;
    for (int i = tid; i < 2304; i += 256)
        gout[i] = Gt[0][i] + Gt[1][i] + Gt[2][i] + Gt[3][i];
}

// ---------------------------------------------------------------------------
// Per (b,h): reduce G partials + norm partials, softmax(G/(nq*nk)*T), then
// M[c, 48h+e] = sum_d w_out[c, 48h+d] * attn[d,e]   (folds final 1x1 conv).
// ---------------------------------------------------------------------------
__global__ void __launch_bounds__(256) attn_m_kernel(
    const float* __restrict__ Gpart,        // [B,4,16,2304]
    const float* __restrict__ nqPart,       // [B,192,32]
    const float* __restrict__ nkPart,       // [B,192,32]
    const float* __restrict__ w_out,        // [192,192] fp32
    const float* __restrict__ temperature,  // [4]
    unsigned short* __restrict__ Mmat)      // [B,192,192] bf16
{
    const int blk = blockIdx.x;
    const int b = blk >> 2, h = blk & 3;
    const int tid = threadIdx.x;
    __shared__ float G[2304];
    __shared__ float At[2304];
    __shared__ float nqv[48], nkv[48];

    const long base = ((long)(b * 4 + h)) * 16;
    for (int i = tid; i < 2304; i += 256) {
        float s = 0.f;
        for (int c = 0; c < 16; ++c) s += Gpart[(base + c) * 2304 + i];
        G[i] = s;
    }
    if (tid < 96) {
        const int isK = tid >= 48;
        const int d = tid - 48 * isK;
        const float* p = (isK ? nkPart : nqPart) + ((long)b * 192 + h * 48 + d) * 32;
        float s = 0.f;
        for (int i = 0; i < 32; ++i) s += p[i];
        const float nrm = fmaxf(sqrtf(s), 1e-12f);
        if (isK) nkv[d] = nrm; else nqv[d] = nrm;
    }
    __syncthreads();

    const float T = temperature[h];
    if (tid < 48) {
        const int d = tid;
        const float scale = T / nqv[d];
        float m = -1e30f;
        for (int e = 0; e < 48; ++e) {
            const float sv = G[d * 48 + e] * scale / nkv[e];
            At[d * 48 + e] = sv;
            m = fmaxf(m, sv);
        }
        float sum = 0.f;
        for (int e = 0; e < 48; ++e) {
            const float ex = expf(At[d * 48 + e] - m);
            At[d * 48 + e] = ex;
            sum += ex;
        }
        const float inv = 1.f / sum;
        for (int e = 0; e < 48; ++e) At[d * 48 + e] *= inv;
    }
    __syncthreads();

    for (int i = tid; i < 192 * 48; i += 256) {
        const int c = i / 48, e = i - (i / 48) * 48;
        const float* wrow = w_out + (long)c * 192 + h * 48;
        float s = 0.f;
        for (int d = 0; d < 48; ++d) s += wrow[d] * At[d * 48 + e];
        Mmat[((long)b * 192 + c) * 192 + h * 48 + e] = f2b(s);
    }
}

// ---------------------------------------------------------------------------
extern "C" void kernel_launch(void* const* d_in, const int* in_sizes, int n_in,
                              void* d_out, int out_size, void* d_ws, size_t ws_size,
                              hipStream_t stream)
{
    const float* f_opt  = (const float*)d_in[0];
    const float* f_sar  = (const float*)d_in[1];
    const float* w_q    = (const float*)d_in[2];
    const float* w_qdw  = (const float*)d_in[3];
    const float* w_kv   = (const float*)d_in[4];
    const float* w_kvdw = (const float*)d_in[5];
    const float* w_out  = (const float*)d_in[6];
    const float* temper = (const float*)d_in[7];
    float* out = (float*)d_out;

    const long N = 16384;
    char* ws = (char*)d_ws;
    size_t off = 0;
    auto alloc = [&](size_t bytes) -> void* {
        void* p = ws + off;
        off = (off + bytes + 255) & ~(size_t)255;
        return p;
    };

    unsigned short* wq_b  = (unsigned short*)alloc((size_t)192 * 192 * 2);
    unsigned short* wkv_b = (unsigned short*)alloc((size_t)384 * 192 * 2);
    unsigned short* Mmat  = (unsigned short*)alloc((size_t)8 * 192 * 192 * 2);
    float* Gpart  = (float*)alloc((size_t)8 * 4 * 16 * 2304 * 4);
    float* nqPart = (float*)alloc((size_t)8 * 192 * 32 * 4);
    float* nkPart = (float*)alloc((size_t)8 * 192 * 32 * 4);
    unsigned short* qbuf  = (unsigned short*)alloc((size_t)8 * 192 * N * 2);
    unsigned short* kvbuf = (unsigned short*)alloc((size_t)8 * 384 * N * 2);

    const size_t fullNeed = off + ((size_t)8 * 192 * N * 2 + 256)
                                + ((size_t)8 * 384 * N * 2 + 256);
    const bool full = (ws_size >= fullNeed);

    unsigned short *q0, *kv0;
    long q0S, kv0S; int nz;
    if (full) {
        q0  = (unsigned short*)alloc((size_t)8 * 192 * N * 2);
        kv0 = (unsigned short*)alloc((size_t)8 * 384 * N * 2);
        q0S = 192 * N; kv0S = 384 * N; nz = 8;
    } else {  // per-batch staging loop, reuse small q0/kv0
        q0  = (unsigned short*)alloc((size_t)192 * N * 2);
        kv0 = (unsigned short*)alloc((size_t)384 * N * 2);
        q0S = 0; kv0S = 0; nz = 1;
    }

    cvt_f2b_kernel<<<dim3((192*192 + 255) / 256), 256, 0, stream>>>(w_q,  wq_b,  192*192);
    cvt_f2b_kernel<<<dim3((384*192 + 255) / 256), 256, 0, stream>>>(w_kv, wkv_b, 384*192);

    const int iters = full ? 1 : 8;
    for (int it = 0; it < iters; ++it) {
        const int b0 = full ? 0 : it;
        conv_gemm<float, unsigned short><<<dim3(256, 1, nz), 256, 0, stream>>>(
            wq_b, f_opt, q0, 0, 192 * N, q0S, b0);
        dw3x3<<<dim3(1536, 1, nz), 256, 0, stream>>>(
            q0, qbuf, w_qdw, nqPart, 192, q0S, 192 * N, b0);
        conv_gemm<float, unsigned short><<<dim3(256, 2, nz), 256, 0, stream>>>(
            wkv_b, f_sar, kv0, 0, 192 * N, kv0S, b0);
        dw3x3<<<dim3(3072, 1, nz), 256, 0, stream>>>(
            kv0, kvbuf, w_kvdw, nkPart, 384, kv0S, 384 * N, b0);
    }

    gram_kernel<<<dim3(16, 4, 8), 256, 0, stream>>>(qbuf, kvbuf, Gpart);
    attn_m_kernel<<<dim3(32), 256, 0, stream>>>(Gpart, nqPart, nkPart, w_out, temper, Mmat);

    // out = M_b @ v  (v = channels 192..383 of kv)
    conv_gemm<unsigned short, float><<<dim3(256, 1, 8), 256, 0, stream>>>(
        Mmat, kvbuf + 192 * N, out, (long)192 * 192, 384 * N, 192 * N, 0);
}